// Round 4
// baseline (698.391 us; speedup 1.0000x reference)
//
#include <hip/hip_runtime.h>
#include <stdint.h>

#define AS1 __attribute__((address_space(1)))
#define AS3 __attribute__((address_space(3)))

typedef __attribute__((ext_vector_type(8))) short short8;
typedef __attribute__((ext_vector_type(4))) float floatx4;

__device__ __forceinline__ unsigned short f2b_rne(float f) {
  union { float f; unsigned u; } c; c.f = f;
  unsigned u = c.u;
  unsigned r = u + 0x7fffu + ((u >> 16) & 1u);
  return (unsigned short)(r >> 16);
}

__device__ __forceinline__ short8 cvt8(float4 a, float4 b) {
  union { short8 s; unsigned u[4]; } r;
  r.u[0] = ((unsigned)f2b_rne(a.y) << 16) | f2b_rne(a.x);
  r.u[1] = ((unsigned)f2b_rne(a.w) << 16) | f2b_rne(a.z);
  r.u[2] = ((unsigned)f2b_rne(b.y) << 16) | f2b_rne(b.x);
  r.u[3] = ((unsigned)f2b_rne(b.w) << 16) | f2b_rne(b.z);
  return r.s;
}

// ===========================================================================
// FRAGMENT-ORDER LAYOUT (for the fast path)
// For a matrix [R][256] (rows = m or weight-col n, k = 0..255):
//   group g = row>>4 (16 rows), chunk ch = k>>3 (8 bf16 = 16 B), r = row&15.
//   elem index = g*4096 + ch*128 + r*8 + (k&7).
// A wave's MFMA fragment (lane = quad*16+lrow reads row lrow, k quad*8..+7 of
// a 32-k slice s) is then the contiguous 1 KB at g*4096 + s*512 + lane*8.
// ===========================================================================

// ---- fp32 [M][256] row-major -> bf16 fragment order -----------------------
__global__ __launch_bounds__(256)
void conv_frag(const float* __restrict__ src, unsigned short* __restrict__ dst) {
  const int g = blockIdx.x;
  const float* s0 = src + (size_t)g * 16 * 256;
  unsigned short* d0 = dst + (size_t)g * 4096;
#pragma unroll
  for (int i = 0; i < 2; ++i) {
    int c = i * 256 + threadIdx.x;      // 0..511
    int row = c >> 5, ch = c & 31;
    const float* gp = s0 + row * 256 + ch * 8;
    float4 x0 = *(const float4*)gp;
    float4 x1 = *(const float4*)(gp + 4);
    *(short8*)(d0 + (size_t)ch * 128 + row * 8) = cvt8(x0, x1);
  }
}

// ---- weight prep, fragment order. n-rows: 0..255 Wv, 256..511 Wso,
// 512..767 Wtso, 768..1023 head-interleaved [Waw|Wtaw] (32-col head groups
// so the joint softmax reduces inside a 16-lane shfl group). ---------------
__global__ void prep_weights_frag(const float* __restrict__ Wv,  const float* __restrict__ bv,
                                  const float* __restrict__ Wso, const float* __restrict__ bso,
                                  const float* __restrict__ Waw, const float* __restrict__ baw,
                                  const float* __restrict__ Wtso,const float* __restrict__ btso,
                                  const float* __restrict__ Wtaw,const float* __restrict__ btaw,
                                  unsigned short* __restrict__ Wtf, float* __restrict__ bcat) {
  int n = blockIdx.x;   // 0..1023
  int k = threadIdx.x;  // 0..255
  const float* W; const float* b; int c, N;
  if (n < 256)      { W = Wv;   b = bv;   c = n;       N = 256; }
  else if (n < 512) { W = Wso;  b = bso;  c = n - 256; N = 256; }
  else if (n < 768) { W = Wtso; b = btso; c = n - 512; N = 256; }
  else {
    int idx = n - 768, h = idx >> 5, w = idx & 31;
    if (w < 16) { W = Waw;  b = baw;  c = h * 16 + w;        N = 128; }
    else        { W = Wtaw; b = btaw; c = h * 16 + (w - 16); N = 128; }
  }
  size_t dst = (size_t)(n >> 4) * 4096 + (size_t)(k >> 3) * 128 + (n & 15) * 8 + (k & 7);
  Wtf[dst] = f2b_rne(W[(size_t)k * N + c]);
  if (k == 0) bcat[n] = b[c];
}

// ---------------------------------------------------------------------------
// Fast-path GEMM: grid (8, M/128). No LDS, no barriers, zero conversion VALU.
// Wave = 64x64 tile = 4x4 MFMA 16x16x32; all fragment loads are per-lane-
// contiguous dwordx4 (1 KB per wave-load). Register double-buffer (s, s+1).
//   nt 0..1 value | 2..3 so | 4..5 tso | 6..7 aw + fused shfl softmax.
// ---------------------------------------------------------------------------
__global__ __launch_bounds__(256, 4)
void gemm_frag(const unsigned short* __restrict__ Qf, const unsigned short* __restrict__ Xf,
               const unsigned short* __restrict__ Wtf, const float* __restrict__ bcat,
               float* __restrict__ out, int M) {
  const int nt = blockIdx.x;     // 0..7
  const int mt = blockIdx.y;
  const unsigned short* A = (nt < 2) ? Xf : Qf;

  const int tid  = threadIdx.x;
  const int lane = tid & 63;
  const int wid  = tid >> 6;
  const int mw   = (wid >> 1) * 64;
  const int nw   = (wid & 1) * 64;
  const int lrow = lane & 15;
  const int quad = lane >> 4;

  const int ga0 = mt * 8 + (wid >> 1) * 4;   // A 16-row-group base
  const int gb0 = nt * 8 + (wid & 1) * 4;    // B 16-row-group base
  const unsigned short* ap = A   + (size_t)ga0 * 4096 + lane * 8;
  const unsigned short* bp = Wtf + (size_t)gb0 * 4096 + lane * 8;

  floatx4 acc[4][4] = {};
  short8 af[2][4], bf[2][4];
#pragma unroll
  for (int mi = 0; mi < 4; ++mi) af[0][mi] = *(const short8*)(ap + mi * 4096);
#pragma unroll
  for (int ni = 0; ni < 4; ++ni) bf[0][ni] = *(const short8*)(bp + ni * 4096);

#pragma unroll
  for (int s = 0; s < 8; ++s) {
    const int cur = s & 1, nxt = cur ^ 1;   // constant after unroll
    if (s < 7) {
#pragma unroll
      for (int mi = 0; mi < 4; ++mi)
        af[nxt][mi] = *(const short8*)(ap + mi * 4096 + (s + 1) * 512);
#pragma unroll
      for (int ni = 0; ni < 4; ++ni)
        bf[nxt][ni] = *(const short8*)(bp + ni * 4096 + (s + 1) * 512);
    }
#pragma unroll
    for (int mi = 0; mi < 4; ++mi)
#pragma unroll
      for (int ni = 0; ni < 4; ++ni)
        acc[mi][ni] = __builtin_amdgcn_mfma_f32_16x16x32_bf16(af[cur][mi], bf[cur][ni], acc[mi][ni], 0, 0, 0);
  }

  const int mBase = mt * 128, nBase = nt * 128;
  // C/D layout: col = lane&15, row = quad*4 + reg (m89-verified)
  if (nt < 6) {
    const int seg  = nt >> 1;
    const int half = nt & 1;
    float* Oseg = out + (size_t)seg * ((size_t)M * 256) + (size_t)half * 128;
#pragma unroll
    for (int ni = 0; ni < 4; ++ni) {
      float bias = bcat[nBase + nw + ni * 16 + lrow];
#pragma unroll
      for (int mi = 0; mi < 4; ++mi) {
#pragma unroll
        for (int r = 0; r < 4; ++r) {
          int row = mBase + mw + mi * 16 + quad * 4 + r;
          int col = nw + ni * 16 + lrow;
          Oseg[(size_t)row * 256 + col] = acc[mi][ni][r] + bias;
        }
      }
    }
  } else {
    float* awc = out + (size_t)3 * ((size_t)M * 256);
    float* awt = awc + (size_t)M * 128;
    float bias[4];
#pragma unroll
    for (int ni = 0; ni < 4; ++ni) bias[ni] = bcat[nBase + nw + ni * 16 + lrow];
    const int hbase = ((nt - 6) * 128 + nw) >> 5;
#pragma unroll
    for (int mi = 0; mi < 4; ++mi) {
#pragma unroll
      for (int r = 0; r < 4; ++r) {
        const int row = mBase + mw + mi * 16 + quad * 4 + r;
#pragma unroll
        for (int hg = 0; hg < 2; ++hg) {
          float a = acc[mi][2 * hg + 0][r] + bias[2 * hg + 0];
          float b = acc[mi][2 * hg + 1][r] + bias[2 * hg + 1];
          float mx = fmaxf(a, b);
          mx = fmaxf(mx, __shfl_xor(mx, 1));
          mx = fmaxf(mx, __shfl_xor(mx, 2));
          mx = fmaxf(mx, __shfl_xor(mx, 4));
          mx = fmaxf(mx, __shfl_xor(mx, 8));
          float ea = __expf(a - mx), eb = __expf(b - mx);
          float ssum = ea + eb;
          ssum += __shfl_xor(ssum, 1);
          ssum += __shfl_xor(ssum, 2);
          ssum += __shfl_xor(ssum, 4);
          ssum += __shfl_xor(ssum, 8);
          float inv = 1.0f / ssum;
          const int h = hbase + hg;
          awc[(size_t)row * 128 + h * 16 + lrow] = ea * inv;
          awt[(size_t)row * 128 + h * 16 + lrow] = eb * inv;
        }
      }
    }
  }
}

// ===========================================================================
// FALLBACK PATH (verified R3 kernels) — used only if ws_size is too small.
// ===========================================================================
__global__ void prep_weights_rows(const float* __restrict__ Wv,  const float* __restrict__ bv,
                                  const float* __restrict__ Wso, const float* __restrict__ bso,
                                  const float* __restrict__ Waw, const float* __restrict__ baw,
                                  const float* __restrict__ Wtso,const float* __restrict__ btso,
                                  const float* __restrict__ Wtaw,const float* __restrict__ btaw,
                                  unsigned short* __restrict__ Wt, float* __restrict__ bcat) {
  int n = blockIdx.x, k = threadIdx.x;
  const float* W; const float* b; int c, N;
  if (n < 256)      { W = Wv;   b = bv;   c = n;       N = 256; }
  else if (n < 512) { W = Wso;  b = bso;  c = n - 256; N = 256; }
  else if (n < 768) { W = Wtso; b = btso; c = n - 512; N = 256; }
  else {
    int idx = n - 768, h = idx >> 5, w = idx & 31;
    if (w < 16) { W = Waw;  b = baw;  c = h * 16 + w;        N = 128; }
    else        { W = Wtaw; b = btaw; c = h * 16 + (w - 16); N = 128; }
  }
  Wt[n * 256 + k] = f2b_rne(W[(size_t)k * N + c]);
  if (k == 0) bcat[n] = b[c];
}

__global__ __launch_bounds__(256, 3)
void gemm_main(const float* __restrict__ Q, const float* __restrict__ X,
               const unsigned short* __restrict__ Wt, const float* __restrict__ bcat,
               float* __restrict__ out, int M) {
  __shared__ __align__(16) unsigned short As[128 * 64];
  __shared__ __align__(16) unsigned short Bs[128 * 64];
  const int nt = blockIdx.x, mt = blockIdx.y;
  const int mBase = mt * 128, nBase = nt * 128;
  const float* A = (nt < 2) ? X : Q;
  const int tid = threadIdx.x, lane = tid & 63, wid = tid >> 6;
  const int mw = (wid >> 1) * 64, nw = (wid & 1) * 64;
  const int lrow = lane & 15, quad = lane >> 4;
  floatx4 acc[4][4] = {};
  const float* Ab = A + (size_t)mBase * 256;
  const unsigned short* Bb = Wt + (size_t)nBase * 256;
  for (int s = 0; s < 4; ++s) {
    const int k0 = s * 64;
    __syncthreads();
#pragma unroll
    for (int j = 0; j < 4; ++j) {
      int ch = j * 256 + tid;
      int r = ch >> 3, kc = ch & 7;
      const unsigned short* g = Bb + (size_t)r * 256 + k0 + ((kc ^ (r & 7)) << 3);
      unsigned ldsoff = (unsigned)((j * 256 + (tid & ~63)) * 16);
      __builtin_amdgcn_global_load_lds((const AS1 void*)g,
                                       (AS3 void*)(((char*)Bs) + ldsoff), 16, 0, 0);
    }
    float4 va[8];
#pragma unroll
    for (int i = 0; i < 8; ++i) {
      int id = i * 256 + tid;
      int r = id >> 4, kc4 = id & 15;
      va[i] = *(const float4*)(Ab + (size_t)r * 256 + k0 + kc4 * 4);
    }
#pragma unroll
    for (int i = 0; i < 8; ++i) {
      int id = i * 256 + tid;
      int r = id >> 4, kc4 = id & 15;
      uint2 pk;
      pk.x = ((unsigned)f2b_rne(va[i].y) << 16) | f2b_rne(va[i].x);
      pk.y = ((unsigned)f2b_rne(va[i].w) << 16) | f2b_rne(va[i].z);
      int idx = r * 64 + ((((kc4 >> 1) ^ (r & 7)) << 3) + (kc4 & 1) * 4);
      *(uint2*)&As[idx] = pk;
    }
    __syncthreads();
    short8 af[2][4], bf[2][4];
#pragma unroll
    for (int t = 0; t < 2; ++t) {
#pragma unroll
      for (int mi = 0; mi < 4; ++mi) {
        int row = mw + mi * 16 + lrow;
        af[t][mi] = *(const short8*)&As[row * 64 + (((t * 4 + quad) ^ (row & 7)) << 3)];
      }
#pragma unroll
      for (int ni = 0; ni < 4; ++ni) {
        int row = nw + ni * 16 + lrow;
        bf[t][ni] = *(const short8*)&Bs[row * 64 + (((t * 4 + quad) ^ (row & 7)) << 3)];
      }
    }
#pragma unroll
    for (int t = 0; t < 2; ++t)
#pragma unroll
      for (int mi = 0; mi < 4; ++mi)
#pragma unroll
        for (int ni = 0; ni < 4; ++ni)
          acc[mi][ni] = __builtin_amdgcn_mfma_f32_16x16x32_bf16(af[t][mi], bf[t][ni], acc[mi][ni], 0, 0, 0);
  }
  if (nt < 6) {
    const int seg = nt >> 1, half = nt & 1;
    float* Oseg = out + (size_t)seg * ((size_t)M * 256) + (size_t)half * 128;
#pragma unroll
    for (int ni = 0; ni < 4; ++ni) {
      float bias = bcat[nBase + nw + ni * 16 + lrow];
#pragma unroll
      for (int mi = 0; mi < 4; ++mi)
#pragma unroll
        for (int r = 0; r < 4; ++r) {
          int row = mBase + mw + mi * 16 + quad * 4 + r;
          int col = nw + ni * 16 + lrow;
          Oseg[(size_t)row * 256 + col] = acc[mi][ni][r] + bias;
        }
    }
  } else {
    float* awc = out + (size_t)3 * ((size_t)M * 256);
    float* awt = awc + (size_t)M * 128;
    float bias[4];
#pragma unroll
    for (int ni = 0; ni < 4; ++ni) bias[ni] = bcat[nBase + nw + ni * 16 + lrow];
    const int hbase = ((nt - 6) * 128 + nw) >> 5;
#pragma unroll
    for (int mi = 0; mi < 4; ++mi)
#pragma unroll
      for (int r = 0; r < 4; ++r) {
        const int row = mBase + mw + mi * 16 + quad * 4 + r;
#pragma unroll
        for (int hg = 0; hg < 2; ++hg) {
          float a = acc[mi][2 * hg + 0][r] + bias[2 * hg + 0];
          float b = acc[mi][2 * hg + 1][r] + bias[2 * hg + 1];
          float mx = fmaxf(a, b);
          mx = fmaxf(mx, __shfl_xor(mx, 1));
          mx = fmaxf(mx, __shfl_xor(mx, 2));
          mx = fmaxf(mx, __shfl_xor(mx, 4));
          mx = fmaxf(mx, __shfl_xor(mx, 8));
          float ea = __expf(a - mx), eb = __expf(b - mx);
          float ssum = ea + eb;
          ssum += __shfl_xor(ssum, 1);
          ssum += __shfl_xor(ssum, 2);
          ssum += __shfl_xor(ssum, 4);
          ssum += __shfl_xor(ssum, 8);
          float inv = 1.0f / ssum;
          const int h = hbase + hg;
          awc[(size_t)row * 128 + h * 16 + lrow] = ea * inv;
          awt[(size_t)row * 128 + h * 16 + lrow] = eb * inv;
        }
      }
  }
}

// ---------------------------------------------------------------------------
extern "C" void kernel_launch(void* const* d_in, const int* in_sizes, int n_in,
                              void* d_out, int out_size, void* d_ws, size_t ws_size,
                              hipStream_t stream) {
  const float* Q    = (const float*)d_in[0];
  const float* Xf32 = (const float*)d_in[1];
  const float* Wv   = (const float*)d_in[2];
  const float* bv   = (const float*)d_in[3];
  const float* Wso  = (const float*)d_in[4];
  const float* bso  = (const float*)d_in[5];
  const float* Waw  = (const float*)d_in[6];
  const float* baw  = (const float*)d_in[7];
  const float* Wtso = (const float*)d_in[8];
  const float* btso = (const float*)d_in[9];
  const float* Wtaw = (const float*)d_in[10];
  const float* btaw = (const float*)d_in[11];
  float* out = (float*)d_out;

  int M = in_sizes[0] / 256;  // 97920

  unsigned short* Wt = (unsigned short*)d_ws;               // 512 KB
  float* bcat = (float*)((char*)d_ws + 1024 * 256 * 2);     // 4 KB
  size_t abytes = (size_t)M * 256 * 2;                      // 50.1 MB each
  size_t need = 1024 * 256 * 2 + 4096 + 2 * abytes;

  if (ws_size >= need) {
    unsigned short* Qf = (unsigned short*)((char*)d_ws + 1024 * 256 * 2 + 4096);
    unsigned short* Xf = (unsigned short*)((char*)Qf + abytes);
    prep_weights_frag<<<1024, 256, 0, stream>>>(Wv, bv, Wso, bso, Waw, baw,
                                                Wtso, btso, Wtaw, btaw, Wt, bcat);
    conv_frag<<<M / 16, 256, 0, stream>>>(Q, Qf);
    conv_frag<<<M / 16, 256, 0, stream>>>(Xf32, Xf);
    dim3 g(8, M / 128);
    gemm_frag<<<g, 256, 0, stream>>>(Qf, Xf, Wt, bcat, out, M);
  } else {
    prep_weights_rows<<<1024, 256, 0, stream>>>(Wv, bv, Wso, bso, Waw, baw,
                                                Wtso, btso, Wtaw, btaw, Wt, bcat);
    dim3 g(8, M / 128);
    gemm_main<<<g, 256, 0, stream>>>(Q, Xf32, Wt, bcat, out, M);
  }
}

// Round 5
// 634.927 us; speedup vs baseline: 1.1000x; 1.1000x over previous
//
#include <hip/hip_runtime.h>
#include <stdint.h>

#define AS1 __attribute__((address_space(1)))
#define AS3 __attribute__((address_space(3)))

typedef __attribute__((ext_vector_type(8))) short short8;
typedef __attribute__((ext_vector_type(4))) float floatx4;

__device__ __forceinline__ unsigned short f2b_rne(float f) {
  union { float f; unsigned u; } c; c.f = f;
  unsigned u = c.u;
  unsigned r = u + 0x7fffu + ((u >> 16) & 1u);
  return (unsigned short)(r >> 16);
}

// ---------------------------------------------------------------------------
// Weight prep: Wt[n][k] = bf16(W_seg[k][c])  (B^T layout, K contiguous)
// rows 0..255=W_val, 256..511=W_so, 512..767=W_tso.
// rows 768..1023: head-interleaved aw layout — idx=n-768, h=idx>>5, w=idx&31:
// w<16 -> W_aw col h*16+w ; w>=16 -> W_taw col h*16+(w-16). Each head's 32
// joint-softmax logits are one contiguous 32-col group -> 16-lane shfl softmax.
// ---------------------------------------------------------------------------
__global__ void prep_weights(const float* __restrict__ Wv,  const float* __restrict__ bv,
                             const float* __restrict__ Wso, const float* __restrict__ bso,
                             const float* __restrict__ Waw, const float* __restrict__ baw,
                             const float* __restrict__ Wtso,const float* __restrict__ btso,
                             const float* __restrict__ Wtaw,const float* __restrict__ btaw,
                             unsigned short* __restrict__ Wt, float* __restrict__ bcat) {
  int n = blockIdx.x;   // 0..1023
  int k = threadIdx.x;  // 0..255
  const float* W; const float* b; int c, N;
  if (n < 256)      { W = Wv;   b = bv;   c = n;       N = 256; }
  else if (n < 512) { W = Wso;  b = bso;  c = n - 256; N = 256; }
  else if (n < 768) { W = Wtso; b = btso; c = n - 512; N = 256; }
  else {
    int idx = n - 768, h = idx >> 5, w = idx & 31;
    if (w < 16) { W = Waw;  b = baw;  c = h * 16 + w;        N = 128; }
    else        { W = Wtaw; b = btaw; c = h * 16 + (w - 16); N = 128; }
  }
  Wt[n * 256 + k] = f2b_rne(W[(size_t)k * N + c]);
  if (k == 0) bcat[n] = b[c];
}

// ---------------------------------------------------------------------------
// Main GEMM, grid (8, M/128), 128x128 tile, BK=32, double-buffered LDS,
// software-pipelined: per k-step, NEXT tile's loads (B via fire-and-forget
// global_load_lds, A via float4->reg) are issued right after the barrier and
// fly during the CURRENT tile's ds_read+MFMA; the A convert + ds_write land
// after the MFMA block. One __syncthreads per k-step (its vmcnt(0) drain is
// free: the convert's auto-wait already drained, B issued before A).
//   nt 0..1 value | 2..3 so | 4..5 tso | 6..7 aw + fused shfl softmax.
// 16B-granule XOR swizzle (chunk ^ (row&3)); B source pre-swizzled so the
// linear global_load_lds dest yields swizzled content (m173 pattern).
// ---------------------------------------------------------------------------
__global__ __launch_bounds__(256, 3)
void gemm_main(const float* __restrict__ Q, const float* __restrict__ X,
               const unsigned short* __restrict__ Wt, const float* __restrict__ bcat,
               float* __restrict__ out, int M) {
  __shared__ __align__(16) unsigned short As[2][128 * 32];  // 2 x 8 KB
  __shared__ __align__(16) unsigned short Bs[2][128 * 32];  // 2 x 8 KB

  const int nt = blockIdx.x;     // 0..7
  const int mt = blockIdx.y;
  const int mBase = mt * 128;
  const int nBase = nt * 128;
  const float* A = (nt < 2) ? X : Q;

  const int tid  = threadIdx.x;
  const int lane = tid & 63;
  const int wid  = tid >> 6;
  const int mw   = (wid >> 1) * 64;
  const int nw   = (wid & 1) * 64;
  const int lrow = lane & 15;
  const int quad = lane >> 4;

  const float* Ab = A + (size_t)mBase * 256;
  const unsigned short* Bb = Wt + (size_t)nBase * 256;

  floatx4 acc[4][4] = {};
  float4 va[2][4];

  // issue B tile s -> Bs[buf]: 128x32 bf16 = 512 x 16B chunks, 2/thread,
  // fire-and-forget DMA (no VGPR round-trip -> deep MLP).
  auto issueB = [&](int s, int buf) {
#pragma unroll
    for (int j = 0; j < 2; ++j) {
      int ch = j * 256 + tid;
      int r = ch >> 2, kc = ch & 3;
      const unsigned short* g = Bb + (size_t)r * 256 + s * 32 + ((kc ^ (r & 3)) << 3);
      char* dst = ((char*)&Bs[buf][0]) + (j * 256 + (tid & ~63)) * 16;
      __builtin_amdgcn_global_load_lds((const AS1 void*)g, (AS3 void*)dst, 16, 0, 0);
    }
  };
  // issue A tile s -> regs: 128x32 fp32 = 1024 float4, 4/thread, coalesced.
  auto issueA = [&](int s, float4* v) {
#pragma unroll
    for (int i = 0; i < 4; ++i) {
      int id = i * 256 + tid;
      int r = id >> 3, kc4 = id & 7;
      v[i] = *(const float4*)(Ab + (size_t)r * 256 + s * 32 + kc4 * 4);
    }
  };
  // convert regs -> swizzled bf16 LDS tile.
  auto writeA = [&](const float4* v, int buf) {
#pragma unroll
    for (int i = 0; i < 4; ++i) {
      int id = i * 256 + tid;
      int r = id >> 3, kc4 = id & 7;
      uint2 pk;
      pk.x = ((unsigned)f2b_rne(v[i].y) << 16) | f2b_rne(v[i].x);
      pk.y = ((unsigned)f2b_rne(v[i].w) << 16) | f2b_rne(v[i].z);
      *(uint2*)&As[buf][r * 32 + ((((kc4 >> 1) ^ (r & 3)) << 3) + (kc4 & 1) * 4)] = pk;
    }
  };

  // ---- prologue: tile 0 staged, then one barrier ----
  issueB(0, 0);
  issueA(0, va[0]);
  writeA(va[0], 0);     // compiler auto-waits va (drains B(0) too — prologue only)
  __syncthreads();

#pragma unroll
  for (int s = 0; s < 8; ++s) {
    const int cur = s & 1, nxt = cur ^ 1;   // literal after unroll
    if (s < 7) {
      issueB(s + 1, nxt);       // in flight across the whole compute phase
      issueA(s + 1, va[nxt]);
    }
    short8 af[4], bf[4];
#pragma unroll
    for (int mi = 0; mi < 4; ++mi) {
      int row = mw + mi * 16 + lrow;
      af[mi] = *(const short8*)&As[cur][row * 32 + ((quad ^ (row & 3)) << 3)];
    }
#pragma unroll
    for (int ni = 0; ni < 4; ++ni) {
      int row = nw + ni * 16 + lrow;
      bf[ni] = *(const short8*)&Bs[cur][row * 32 + ((quad ^ (row & 3)) << 3)];
    }
#pragma unroll
    for (int mi = 0; mi < 4; ++mi)
#pragma unroll
      for (int ni = 0; ni < 4; ++ni)
        acc[mi][ni] = __builtin_amdgcn_mfma_f32_16x16x32_bf16(af[mi], bf[ni], acc[mi][ni], 0, 0, 0);
    if (s < 7) {
      writeA(va[nxt], nxt);     // auto vmcnt wait covers B(s+1) (issued earlier)
      __syncthreads();          // ONE barrier per k-step; dbuf makes it sufficient
    }
  }

  // ---- epilogue (verified R3): C/D col=lane&15, row=quad*4+reg ----
  if (nt < 6) {
    const int seg  = nt >> 1;
    const int half = nt & 1;
    float* Oseg = out + (size_t)seg * ((size_t)M * 256) + (size_t)half * 128;
#pragma unroll
    for (int ni = 0; ni < 4; ++ni) {
      float bias = bcat[nBase + nw + ni * 16 + lrow];
#pragma unroll
      for (int mi = 0; mi < 4; ++mi) {
#pragma unroll
        for (int r = 0; r < 4; ++r) {
          int row = mBase + mw + mi * 16 + quad * 4 + r;
          int col = nw + ni * 16 + lrow;
          Oseg[(size_t)row * 256 + col] = acc[mi][ni][r] + bias;
        }
      }
    }
  } else {
    // ---- aw: joint softmax over 32 logits per (row, head); wave = 2 heads.
    float* awc = out + (size_t)3 * ((size_t)M * 256);
    float* awt = awc + (size_t)M * 128;
    float bias[4];
#pragma unroll
    for (int ni = 0; ni < 4; ++ni) bias[ni] = bcat[nBase + nw + ni * 16 + lrow];
    const int hbase = ((nt - 6) * 128 + nw) >> 5;
#pragma unroll
    for (int mi = 0; mi < 4; ++mi) {
#pragma unroll
      for (int r = 0; r < 4; ++r) {
        const int row = mBase + mw + mi * 16 + quad * 4 + r;
#pragma unroll
        for (int hg = 0; hg < 2; ++hg) {
          float a = acc[mi][2 * hg + 0][r] + bias[2 * hg + 0];   // caw logit
          float b = acc[mi][2 * hg + 1][r] + bias[2 * hg + 1];   // taw logit
          float mx = fmaxf(a, b);
          mx = fmaxf(mx, __shfl_xor(mx, 1));
          mx = fmaxf(mx, __shfl_xor(mx, 2));
          mx = fmaxf(mx, __shfl_xor(mx, 4));
          mx = fmaxf(mx, __shfl_xor(mx, 8));
          float ea = __expf(a - mx), eb = __expf(b - mx);
          float ssum = ea + eb;
          ssum += __shfl_xor(ssum, 1);
          ssum += __shfl_xor(ssum, 2);
          ssum += __shfl_xor(ssum, 4);
          ssum += __shfl_xor(ssum, 8);
          float inv = 1.0f / ssum;
          const int h = hbase + hg;
          awc[(size_t)row * 128 + h * 16 + lrow] = ea * inv;
          awt[(size_t)row * 128 + h * 16 + lrow] = eb * inv;
        }
      }
    }
  }
}

// ---------------------------------------------------------------------------
extern "C" void kernel_launch(void* const* d_in, const int* in_sizes, int n_in,
                              void* d_out, int out_size, void* d_ws, size_t ws_size,
                              hipStream_t stream) {
  const float* Q    = (const float*)d_in[0];
  const float* Xf   = (const float*)d_in[1];
  const float* Wv   = (const float*)d_in[2];
  const float* bv   = (const float*)d_in[3];
  const float* Wso  = (const float*)d_in[4];
  const float* bso  = (const float*)d_in[5];
  const float* Waw  = (const float*)d_in[6];
  const float* baw  = (const float*)d_in[7];
  const float* Wtso = (const float*)d_in[8];
  const float* btso = (const float*)d_in[9];
  const float* Wtaw = (const float*)d_in[10];
  const float* btaw = (const float*)d_in[11];
  float* out = (float*)d_out;

  unsigned short* Wt = (unsigned short*)d_ws;               // 512 KB
  float* bcat = (float*)((char*)d_ws + 1024 * 256 * 2);     // 4 KB

  int M = in_sizes[0] / 256;  // 97920

  prep_weights<<<1024, 256, 0, stream>>>(Wv, bv, Wso, bso, Waw, baw,
                                         Wtso, btso, Wtaw, btaw, Wt, bcat);

  dim3 g(8, M / 128);  // nt fastest: all 8 n-tiles of an m-panel co-temporal
  gemm_main<<<g, 256, 0, stream>>>(Q, Xf, Wt, bcat, out, M);
}

// Round 6
// 598.611 us; speedup vs baseline: 1.1667x; 1.0607x over previous
//
#include <hip/hip_runtime.h>
#include <stdint.h>

#define AS1 __attribute__((address_space(1)))
#define AS3 __attribute__((address_space(3)))

typedef __attribute__((ext_vector_type(8))) short short8;
typedef __attribute__((ext_vector_type(4))) float floatx4;

__device__ __forceinline__ unsigned short f2b_rne(float f) {
  union { float f; unsigned u; } c; c.f = f;
  unsigned u = c.u;
  unsigned r = u + 0x7fffu + ((u >> 16) & 1u);
  return (unsigned short)(r >> 16);
}

// ---------------------------------------------------------------------------
// Weight prep: Wt[n][k] = bf16(W_seg[k][c])  (B^T layout, K contiguous)
// rows 0..255=W_val, 256..511=W_so, 512..767=W_tso.
// rows 768..1023: head-interleaved aw layout — idx=n-768, h=idx>>5, w=idx&31:
// w<16 -> W_aw col h*16+w ; w>=16 -> W_taw col h*16+(w-16). Each head's 32
// joint-softmax logits are one contiguous 32-col group -> 16-lane shfl softmax.
// ---------------------------------------------------------------------------
__global__ void prep_weights(const float* __restrict__ Wv,  const float* __restrict__ bv,
                             const float* __restrict__ Wso, const float* __restrict__ bso,
                             const float* __restrict__ Waw, const float* __restrict__ baw,
                             const float* __restrict__ Wtso,const float* __restrict__ btso,
                             const float* __restrict__ Wtaw,const float* __restrict__ btaw,
                             unsigned short* __restrict__ Wt, float* __restrict__ bcat) {
  int n = blockIdx.x;   // 0..1023
  int k = threadIdx.x;  // 0..255
  const float* W; const float* b; int c, N;
  if (n < 256)      { W = Wv;   b = bv;   c = n;       N = 256; }
  else if (n < 512) { W = Wso;  b = bso;  c = n - 256; N = 256; }
  else if (n < 768) { W = Wtso; b = btso; c = n - 512; N = 256; }
  else {
    int idx = n - 768, h = idx >> 5, w = idx & 31;
    if (w < 16) { W = Waw;  b = baw;  c = h * 16 + w;        N = 128; }
    else        { W = Wtaw; b = btaw; c = h * 16 + (w - 16); N = 128; }
  }
  Wt[n * 256 + k] = f2b_rne(W[(size_t)k * N + c]);
  if (k == 0) bcat[n] = b[c];
}

// ---------------------------------------------------------------------------
// Main GEMM, 128x128 tile, BK=64 (R3-verified body), with XCD-aware block
// remap: the 8 n-tile blocks sharing one A-panel are placed on ONE XCD so
// the panel is fetched into that XCD's L2 once (instead of 8 L3 trips).
//   id = x + 8y (hw dispatch order, round-robins XCDs by id%8)
//   c = id&7 (target XCD), j = id>>3, w = c*gridDim.y + j  (bijective)
//   mt = w>>3, nt = w&7  -> consecutive w (one panel) share c.
//   nt 0..1 value | 2..3 so | 4..5 tso | 6..7 aw + fused shfl softmax.
// ---------------------------------------------------------------------------
__global__ __launch_bounds__(256, 3)
void gemm_main(const float* __restrict__ Q, const float* __restrict__ X,
               const unsigned short* __restrict__ Wt, const float* __restrict__ bcat,
               float* __restrict__ out, int M) {
  __shared__ __align__(16) unsigned short As[128 * 64];  // 16 KB
  __shared__ __align__(16) unsigned short Bs[128 * 64];  // 16 KB

  // ---- XCD-locality remap (bijective) ----
  const int id = blockIdx.x + 8 * blockIdx.y;
  const int w  = (id & 7) * gridDim.y + (id >> 3);
  const int nt = w & 7;
  const int mt = w >> 3;

  const int mBase = mt * 128;
  const int nBase = nt * 128;
  const float* A = (nt < 2) ? X : Q;

  const int tid  = threadIdx.x;
  const int lane = tid & 63;
  const int wid  = tid >> 6;
  const int mw   = (wid >> 1) * 64;
  const int nw   = (wid & 1) * 64;
  const int lrow = lane & 15;
  const int quad = lane >> 4;

  floatx4 acc[4][4] = {};

  const float* Ab = A + (size_t)mBase * 256;
  const unsigned short* Bb = Wt + (size_t)nBase * 256;

  for (int s = 0; s < 4; ++s) {
    const int k0 = s * 64;
    __syncthreads();
    // ---- B stage: 128x64 bf16 = 1024 x 16B chunks, 4/thread.
    // LDS dest linear; global source column pre-swizzled (m173 pattern).
#pragma unroll
    for (int j = 0; j < 4; ++j) {
      int ch = j * 256 + tid;
      int r = ch >> 3, kc = ch & 7;
      const unsigned short* g = Bb + (size_t)r * 256 + k0 + ((kc ^ (r & 7)) << 3);
      unsigned ldsoff = (unsigned)((j * 256 + (tid & ~63)) * 16);
      __builtin_amdgcn_global_load_lds((const AS1 void*)g,
                                       (AS3 void*)(((char*)Bs) + ldsoff), 16, 0, 0);
    }
    // ---- A stage: 128x64 fp32 -> bf16: 2048 float4 chunks, 8/thread ----
    float4 va[8];
#pragma unroll
    for (int i = 0; i < 8; ++i) {
      int id2 = i * 256 + tid;
      int r = id2 >> 4, kc4 = id2 & 15;
      va[i] = *(const float4*)(Ab + (size_t)r * 256 + k0 + kc4 * 4);
    }
#pragma unroll
    for (int i = 0; i < 8; ++i) {
      int id2 = i * 256 + tid;
      int r = id2 >> 4, kc4 = id2 & 15;
      uint2 pk;
      pk.x = ((unsigned)f2b_rne(va[i].y) << 16) | f2b_rne(va[i].x);
      pk.y = ((unsigned)f2b_rne(va[i].w) << 16) | f2b_rne(va[i].z);
      int idx = r * 64 + ((((kc4 >> 1) ^ (r & 7)) << 3) + (kc4 & 1) * 4);
      *(uint2*)&As[idx] = pk;
    }
    __syncthreads();
    // ---- compute: wave does 64x64 = 4x4 of 16x16x32, two k-halves ----
    short8 af[2][4], bf[2][4];
#pragma unroll
    for (int t = 0; t < 2; ++t) {
#pragma unroll
      for (int mi = 0; mi < 4; ++mi) {
        int row = mw + mi * 16 + lrow;
        af[t][mi] = *(const short8*)&As[row * 64 + (((t * 4 + quad) ^ (row & 7)) << 3)];
      }
#pragma unroll
      for (int ni = 0; ni < 4; ++ni) {
        int row = nw + ni * 16 + lrow;
        bf[t][ni] = *(const short8*)&Bs[row * 64 + (((t * 4 + quad) ^ (row & 7)) << 3)];
      }
    }
#pragma unroll
    for (int t = 0; t < 2; ++t)
#pragma unroll
      for (int mi = 0; mi < 4; ++mi)
#pragma unroll
        for (int ni = 0; ni < 4; ++ni)
          acc[mi][ni] = __builtin_amdgcn_mfma_f32_16x16x32_bf16(af[t][mi], bf[t][ni], acc[mi][ni], 0, 0, 0);
  }

  // C/D layout: col = lane&15, row = quad*4 + reg (m89-verified)
  if (nt < 6) {
    const int seg  = nt >> 1;
    const int half = nt & 1;
    float* Oseg = out + (size_t)seg * ((size_t)M * 256) + (size_t)half * 128;
#pragma unroll
    for (int ni = 0; ni < 4; ++ni) {
      float bias = bcat[nBase + nw + ni * 16 + lrow];
#pragma unroll
      for (int mi = 0; mi < 4; ++mi) {
#pragma unroll
        for (int r = 0; r < 4; ++r) {
          int row = mBase + mw + mi * 16 + quad * 4 + r;
          int col = nw + ni * 16 + lrow;
          Oseg[(size_t)row * 256 + col] = acc[mi][ni][r] + bias;
        }
      }
    }
  } else {
    // ---- aw: joint softmax over 32 logits per (row, head); wave = 2 heads.
    float* awc = out + (size_t)3 * ((size_t)M * 256);
    float* awt = awc + (size_t)M * 128;
    float bias[4];
#pragma unroll
    for (int ni = 0; ni < 4; ++ni) bias[ni] = bcat[nBase + nw + ni * 16 + lrow];
    const int hbase = ((nt - 6) * 128 + nw) >> 5;
#pragma unroll
    for (int mi = 0; mi < 4; ++mi) {
#pragma unroll
      for (int r = 0; r < 4; ++r) {
        const int row = mBase + mw + mi * 16 + quad * 4 + r;
#pragma unroll
        for (int hg = 0; hg < 2; ++hg) {
          float a = acc[mi][2 * hg + 0][r] + bias[2 * hg + 0];   // caw logit
          float b = acc[mi][2 * hg + 1][r] + bias[2 * hg + 1];   // taw logit
          float mx = fmaxf(a, b);
          mx = fmaxf(mx, __shfl_xor(mx, 1));
          mx = fmaxf(mx, __shfl_xor(mx, 2));
          mx = fmaxf(mx, __shfl_xor(mx, 4));
          mx = fmaxf(mx, __shfl_xor(mx, 8));
          float ea = __expf(a - mx), eb = __expf(b - mx);
          float ssum = ea + eb;
          ssum += __shfl_xor(ssum, 1);
          ssum += __shfl_xor(ssum, 2);
          ssum += __shfl_xor(ssum, 4);
          ssum += __shfl_xor(ssum, 8);
          float inv = 1.0f / ssum;
          const int h = hbase + hg;
          awc[(size_t)row * 128 + h * 16 + lrow] = ea * inv;
          awt[(size_t)row * 128 + h * 16 + lrow] = eb * inv;
        }
      }
    }
  }
}

// ---------------------------------------------------------------------------
extern "C" void kernel_launch(void* const* d_in, const int* in_sizes, int n_in,
                              void* d_out, int out_size, void* d_ws, size_t ws_size,
                              hipStream_t stream) {
  const float* Q    = (const float*)d_in[0];
  const float* Xf   = (const float*)d_in[1];
  const float* Wv   = (const float*)d_in[2];
  const float* bv   = (const float*)d_in[3];
  const float* Wso  = (const float*)d_in[4];
  const float* bso  = (const float*)d_in[5];
  const float* Waw  = (const float*)d_in[6];
  const float* baw  = (const float*)d_in[7];
  const float* Wtso = (const float*)d_in[8];
  const float* btso = (const float*)d_in[9];
  const float* Wtaw = (const float*)d_in[10];
  const float* btaw = (const float*)d_in[11];
  float* out = (float*)d_out;

  unsigned short* Wt = (unsigned short*)d_ws;               // 512 KB
  float* bcat = (float*)((char*)d_ws + 1024 * 256 * 2);     // 4 KB

  int M = in_sizes[0] / 256;  // 97920

  prep_weights<<<1024, 256, 0, stream>>>(Wv, bv, Wso, bso, Waw, baw,
                                         Wtso, btso, Wtaw, btaw, Wt, bcat);

  dim3 g(8, M / 128);  // remapped in-kernel for XCD L2 panel locality
  gemm_main<<<g, 256, 0, stream>>>(Q, Xf, Wt, bcat, out, M);
}